// Round 5
// baseline (583.786 us; speedup 1.0000x reference)
//
#include <hip/hip_runtime.h>
#include <math.h>

// ---------------------------------------------------------------------------
// AttentionNet weighted-anchor aggregator.
//   x:  (8, 448, 448, 3) f32
//   wp3:(8, 6, 4, 14, 14) f32   wp4:(8, 6, 4, 7, 7) f32   wp5:(8, 9, 4, 4, 4) f32
//   out:(32, 224, 224, 3) f32 = sum over 21 configs of
//        resize_bilinear( einsum('bkij,bihjwc->bkhwc', w, patches), 224,224 )
//
// Phase 0a: init_tables — normalized zero-padded 4-tap weights + i0.
// Phase 0b: transpose_w — weights to [cfg][b][grid][k0..k3] float4.
// Phase A : agg_all — ONE dispatch, block-uniform layer switch into templated
//           bodies; weights staged in LDS (1 ds_read_b128/tap); each thread
//           computes 4 consecutive w-pixels (amortizes weight read 4x);
//           bf16x4 (8 B/px) out.
// Phase B : resize_kernel — pipelined cfg loop (round 4 structure), region
//           stored as uint2 bf16 (ds b64, zero conflicts), unpack in taps.
// ---------------------------------------------------------------------------

#define BATCH 8
#define KK 4
#define OUT_HW 224
#define IMG_HW 448
#define NCFG 21

#define WTBL_BYTES (NCFG * 2 * OUT_HW * 16)     // 150528
#define ITBL_BYTES (NCFG * 2 * OUT_HW * 4)      // 37632
#define WT_OFF_BYTES (WTBL_BYTES + ITBL_BYTES)  // 188160
#define WT_F4 12912                             // 8 * (6*196 + 6*49 + 9*16)
#define AGG_OFF_BYTES (WT_OFF_BYTES + WT_F4 * 16)  // 394752 (16B aligned)

#define REGION_PX 640                           // max window = 580 px

struct CfgEntry {          // resize view of a config
    int kh, kw;
    int mth, mtw;          // max tap count per dim (2..4)
    int tbl;               // global cfg index (table lookup)
    int ws_off;            // px (uint2) offset in agg region
};

struct GroupArgs {
    CfgEntry e[NCFG];
    int n;
};

struct ACfg {              // agg view of a config
    int kh, kw, p0, p1;
    int qpr;               // quads (4px) per row = ceil(kw/4)
    int layer;             // 0=p3, 1=p4, 2=p5
    int wt_off;            // float4 offset of transposed weights
    int ws_off;            // px offset in agg region
    int block_start;
    int blocks_per_img;    // ceil(kh*qpr/256)
};

struct AggArgs {
    ACfg e[NCFG];
    int n;
};

struct TablesArgs { int kh[NCFG]; int kw[NCFG]; };

struct TrArgs {
    int layer[NCFG];
    int anchor[NCFG];
    int gsz[NCFG];
    int wt_off[NCFG];
};

struct F12 { float f[12]; };

__device__ inline unsigned int bf16_rne(float f) {
    unsigned int u = __float_as_uint(f);
    return (u + 0x7fffu + ((u >> 16) & 1u)) >> 16;
}

// ---------------------------------------------------------------------------
// Phase 0a: tap tables. jax.image.resize('bilinear', antialias=True):
//   inv=in/out; ks=max(inv,1); sf=(o+0.5)*inv-0.5; taps i in
//   [ceil(sf-ks), floor(sf+ks)] clamped, w=max(0,1-|i-sf|/ks) normalized.
// ---------------------------------------------------------------------------
__global__ __launch_bounds__(256) void init_tables(float4* __restrict__ wtbl,
                                                   int* __restrict__ itbl,
                                                   TablesArgs t) {
    int cfg = blockIdx.x >> 1;
    int dim = blockIdx.x & 1;
    int o = threadIdx.x;
    if (o >= OUT_HW) return;
    int n = dim ? t.kw[cfg] : t.kh[cfg];

    float inv = (float)(1.0 / ((double)OUT_HW / (double)n));
    float ks  = inv > 1.f ? inv : 1.f;
    float rks = 1.f / ks;
    float sf  = ((float)o + 0.5f) * inv - 0.5f;
    int i0 = (int)ceilf(sf - ks);  if (i0 < 0) i0 = 0;
    int i1 = (int)floorf(sf + ks); if (i1 > n - 1) i1 = n - 1;
    float sum = 0.f;
    for (int i = i0; i <= i1; ++i) {
        float v = 1.f - fabsf((float)i - sf) * rks;
        sum += (v > 0.f ? v : 0.f);
    }
    float rsum = 1.f / sum;
    float w[4];
#pragma unroll
    for (int d = 0; d < 4; ++d) {
        int i = i0 + d;
        float v = 0.f;
        if (i <= i1) {
            v = 1.f - fabsf((float)i - sf) * rks;
            v = (v > 0.f ? v : 0.f) * rsum;
        }
        w[d] = v;
    }
    int idx = cfg * (2 * OUT_HW) + dim * OUT_HW + o;
    wtbl[idx] = make_float4(w[0], w[1], w[2], w[3]);
    itbl[idx] = i0;
}

// ---------------------------------------------------------------------------
// Phase 0b: transpose weights (B,A,K,gh,gw) -> per cfg [b][g][k0..k3] float4.
// ---------------------------------------------------------------------------
__global__ __launch_bounds__(256) void transpose_w(
        const float* __restrict__ wp3, const float* __restrict__ wp4,
        const float* __restrict__ wp5, float4* __restrict__ wT, TrArgs t) {
    int cfg = blockIdx.x;
    int b = blockIdx.y;
    int gsz = t.gsz[cfg];
    const float* base;
    int A;
    if (t.layer[cfg] == 0)      { base = wp3; A = 6; }
    else if (t.layer[cfg] == 1) { base = wp4; A = 6; }
    else                        { base = wp5; A = 9; }
    const float* src = base + (size_t)(b * A + t.anchor[cfg]) * (KK * gsz);
    for (int g = threadIdx.x; g < gsz; g += 256) {
        wT[t.wt_off[cfg] + b * gsz + g] =
            make_float4(src[0 * gsz + g], src[1 * gsz + g],
                        src[2 * gsz + g], src[3 * gsz + g]);
    }
}

// ---------------------------------------------------------------------------
// Agg body: thread computes 4 consecutive w-pixels of one agg row.
//   acc[t][k][c] += wlds[i*GW+j].k * x[row(i), col0(j)+t, c]
// ---------------------------------------------------------------------------
template <int GH, int GW, int STRIDE>
__device__ inline void agg_body(const ACfg& c, int b, int h, int w0,
                                const float* __restrict__ xb,
                                const float4* __restrict__ wlds,
                                uint2* __restrict__ agg) {
    float acc[4][4][3];
#pragma unroll
    for (int t = 0; t < 4; ++t)
#pragma unroll
        for (int k = 0; k < 4; ++k) {
            acc[t][k][0] = 0.f; acc[t][k][1] = 0.f; acc[t][k][2] = 0.f;
        }

    const int rb = h - c.p0;
    const int cb = w0 - c.p1;

#pragma unroll
    for (int i = 0; i < GH; ++i) {
        int row = rb + i * STRIDE;
        if ((unsigned)row < (unsigned)IMG_HW) {
            const float* xr = xb + (size_t)row * (IMG_HW * 3);
#pragma unroll
            for (int j = 0; j < GW; ++j) {
                int col0 = cb + j * STRIDE;
                float xv[12];
                if ((unsigned)col0 <= (unsigned)(IMG_HW - 4)) {
                    F12 v = *(const F12*)(xr + (size_t)col0 * 3);
#pragma unroll
                    for (int q = 0; q < 12; ++q) xv[q] = v.f[q];
                } else {
#pragma unroll
                    for (int t = 0; t < 4; ++t) {
                        int col = col0 + t;
                        bool ok = (unsigned)col < (unsigned)IMG_HW;
                        xv[t * 3 + 0] = ok ? xr[(size_t)col * 3 + 0] : 0.f;
                        xv[t * 3 + 1] = ok ? xr[(size_t)col * 3 + 1] : 0.f;
                        xv[t * 3 + 2] = ok ? xr[(size_t)col * 3 + 2] : 0.f;
                    }
                }
                float4 wk = wlds[i * GW + j];
#pragma unroll
                for (int t = 0; t < 4; ++t) {
                    float x0 = xv[t * 3 + 0], x1 = xv[t * 3 + 1], x2 = xv[t * 3 + 2];
                    acc[t][0][0] = fmaf(wk.x, x0, acc[t][0][0]);
                    acc[t][0][1] = fmaf(wk.x, x1, acc[t][0][1]);
                    acc[t][0][2] = fmaf(wk.x, x2, acc[t][0][2]);
                    acc[t][1][0] = fmaf(wk.y, x0, acc[t][1][0]);
                    acc[t][1][1] = fmaf(wk.y, x1, acc[t][1][1]);
                    acc[t][1][2] = fmaf(wk.y, x2, acc[t][1][2]);
                    acc[t][2][0] = fmaf(wk.z, x0, acc[t][2][0]);
                    acc[t][2][1] = fmaf(wk.z, x1, acc[t][2][1]);
                    acc[t][2][2] = fmaf(wk.z, x2, acc[t][2][2]);
                    acc[t][3][0] = fmaf(wk.w, x0, acc[t][3][0]);
                    acc[t][3][1] = fmaf(wk.w, x1, acc[t][3][1]);
                    acc[t][3][2] = fmaf(wk.w, x2, acc[t][3][2]);
                }
            }
        }
    }

    const int npix = c.kh * c.kw;
    const int rem = c.kw - w0;           // >=1
#pragma unroll
    for (int k = 0; k < 4; ++k) {
        size_t base = (size_t)c.ws_off + (size_t)(b * KK + k) * npix
                    + (size_t)h * c.kw + w0;
        uint2 o[4];
#pragma unroll
        for (int t = 0; t < 4; ++t) {
            o[t].x = bf16_rne(acc[t][k][0]) | (bf16_rne(acc[t][k][1]) << 16);
            o[t].y = bf16_rne(acc[t][k][2]);
        }
        if (rem >= 4) {
            agg[base + 0] = o[0]; agg[base + 1] = o[1];
            agg[base + 2] = o[2]; agg[base + 3] = o[3];
        } else {
            for (int t = 0; t < rem; ++t) agg[base + t] = o[t];
        }
    }
}

// ---------------------------------------------------------------------------
// Phase A: one dispatch for all configs. Block-uniform layer switch.
// ---------------------------------------------------------------------------
__global__ __launch_bounds__(256) void agg_all(
        const float* __restrict__ x,
        const float4* __restrict__ wT,
        uint2* __restrict__ agg,
        AggArgs a) {
    int bid = blockIdx.x;
    int ci = 0;
    while (ci + 1 < a.n && bid >= a.e[ci + 1].block_start) ci++;
    const ACfg c = a.e[ci];
    int local = bid - c.block_start;
    int b     = local / c.blocks_per_img;
    int sblk  = local - b * c.blocks_per_img;

    __shared__ float4 wlds[196];
    int gsz = (c.layer == 0) ? 196 : (c.layer == 1) ? 49 : 16;
    for (int t = threadIdx.x; t < gsz; t += 256)
        wlds[t] = wT[c.wt_off + b * gsz + t];
    __syncthreads();

    int qidx = sblk * 256 + (int)threadIdx.x;
    if (qidx >= c.kh * c.qpr) return;
    int h  = qidx / c.qpr;
    int w0 = (qidx - h * c.qpr) * 4;

    const float* xb = x + (size_t)b * (IMG_HW * IMG_HW * 3);
    if (c.layer == 0)      agg_body<14, 14, 32>(c, b, h, w0, xb, wlds, agg);
    else if (c.layer == 1) agg_body<7, 7, 64>(c, b, h, w0, xb, wlds, agg);
    else                   agg_body<4, 4, 128>(c, b, h, w0, xb, wlds, agg);
}

// ---------------------------------------------------------------------------
// Tap micro-kernel: TH x TW taps from the uint2 (bf16x3) LDS region.
// ---------------------------------------------------------------------------
template <int TH, int TW>
__device__ inline void taps(const uint2* __restrict__ rp0, int rcols,
                            float4 wh4, float4 ww4,
                            float& a0, float& a1, float& a2) {
    const float* wh = (const float*)&wh4;
    const float* ww = (const float*)&ww4;
#pragma unroll
    for (int d = 0; d < TH; ++d) {
        const uint2* rp = rp0 + d * rcols;
        float r0 = 0.f, r1 = 0.f, r2 = 0.f;
#pragma unroll
        for (int e = 0; e < TW; ++e) {
            uint2 v = rp[e];
            float c0 = __uint_as_float(v.x << 16);
            float c1 = __uint_as_float(v.x & 0xffff0000u);
            float c2 = __uint_as_float(v.y << 16);
            float w = ww[e];
            r0 = fmaf(w, c0, r0);
            r1 = fmaf(w, c1, r1);
            r2 = fmaf(w, c2, r2);
        }
        a0 = fmaf(wh[d], r0, a0);
        a1 = fmaf(wh[d], r1, a1);
        a2 = fmaf(wh[d], r2, a2);
    }
}

struct Win { int ri0, ci0, rrows, rcols; };

// ---------------------------------------------------------------------------
// Phase B: block = 16x16 output tile for one bk. Pipelined cfg loop:
//   round c: [barrier A] ds_write window c (from regs) [barrier B]
//            issue global loads for window c+1 -> regs; taps for cfg c.
// ---------------------------------------------------------------------------
__global__ __launch_bounds__(256) void resize_kernel(
        const uint2* __restrict__ agg,
        const float4* __restrict__ wtbl,
        const int* __restrict__ itbl,
        float* __restrict__ out,
        GroupArgs g, int accumulate) {
    const int tid = threadIdx.x;
    const int tx = tid & 15;
    const int ty = tid >> 4;
    const int xo = blockIdx.x * 16 + tx;
    const int yo = blockIdx.y * 16 + ty;
    const int bk = blockIdx.z;

    __shared__ float4 wlds[NCFG * 32];
    __shared__ int    ilds[NCFG * 32];
    __shared__ uint2  region[REGION_PX];

    const int nent = g.n * 32;
    for (int e = tid; e < nent; e += 256) {
        int ci  = e >> 5;
        int r   = e & 31;
        int isW = r >> 4;
        int idx = r & 15;
        int base_o = isW ? (blockIdx.x * 16) : (blockIdx.y * 16);
        int src = g.e[ci].tbl * (2 * OUT_HW) + isW * OUT_HW + base_o + idx;
        wlds[ci * 32 + r] = wtbl[src];
        ilds[ci * 32 + r] = itbl[src];
    }
    __syncthreads();

    const int scc = tid & 31;      // staging col lane
    const int srw = tid >> 5;      // staging row base (8 rows/step)

    uint2 sreg[4];
    Win wn, wc;

    // prologue: issue loads for cfg 0
    {
        const CfgEntry c0 = g.e[0];
        int ri0 = ilds[0 * 32 + 0];
        int ri1 = ilds[0 * 32 + 15] + c0.mth - 1;
        int ci0 = ilds[0 * 32 + 16];
        int ci1 = ilds[0 * 32 + 31] + c0.mtw - 1;
        wn.ri0 = ri0; wn.ci0 = ci0;
        wn.rrows = ri1 - ri0 + 1; wn.rcols = ci1 - ci0 + 1;
        const uint2* base = agg + (size_t)c0.ws_off + (size_t)bk * c0.kh * c0.kw;
        int gj = ci0 + scc; if (gj > c0.kw - 1) gj = c0.kw - 1;
        bool cok = scc < wn.rcols;
#pragma unroll
        for (int s = 0; s < 4; ++s) {
            int r = srw + s * 8;
            if (cok && r < wn.rrows) {
                int gi = ri0 + r; if (gi > c0.kh - 1) gi = c0.kh - 1;
                sreg[s] = base[(size_t)gi * c0.kw + gj];
            }
        }
    }

    size_t obase = (((size_t)bk * OUT_HW + yo) * OUT_HW + xo) * 3;
    float a0, a1, a2;
    if (accumulate) { a0 = out[obase]; a1 = out[obase + 1]; a2 = out[obase + 2]; }
    else            { a0 = 0.f; a1 = 0.f; a2 = 0.f; }

    for (int c = 0; c < g.n; ++c) {
        wc = wn;
        __syncthreads();   // A: taps c-1 done; sreg loads drained here
        {
            bool cok = scc < wc.rcols;
#pragma unroll
            for (int s = 0; s < 4; ++s) {
                int r = srw + s * 8;
                if (cok && r < wc.rrows)
                    region[r * wc.rcols + scc] = sreg[s];
            }
        }
        __syncthreads();   // B: region visible

        if (c + 1 < g.n) {
            const CfgEntry cn = g.e[c + 1];
            int ri0 = ilds[(c + 1) * 32 + 0];
            int ri1 = ilds[(c + 1) * 32 + 15] + cn.mth - 1;
            int ci0 = ilds[(c + 1) * 32 + 16];
            int ci1 = ilds[(c + 1) * 32 + 31] + cn.mtw - 1;
            wn.ri0 = ri0; wn.ci0 = ci0;
            wn.rrows = ri1 - ri0 + 1; wn.rcols = ci1 - ci0 + 1;
            const uint2* base = agg + (size_t)cn.ws_off + (size_t)bk * cn.kh * cn.kw;
            int gj = ci0 + scc; if (gj > cn.kw - 1) gj = cn.kw - 1;
            bool cok = scc < wn.rcols;
#pragma unroll
            for (int s = 0; s < 4; ++s) {
                int r = srw + s * 8;
                if (cok && r < wn.rrows) {
                    int gi = ri0 + r; if (gi > cn.kh - 1) gi = cn.kh - 1;
                    sreg[s] = base[(size_t)gi * cn.kw + gj];
                }
            }
        }

        // taps for cfg c
        float4 wh4 = wlds[c * 32 + ty];
        float4 ww4 = wlds[c * 32 + 16 + tx];
        int i0 = ilds[c * 32 + ty];
        int j0 = ilds[c * 32 + 16 + tx];
        const uint2* rp0 = region + (i0 - wc.ri0) * wc.rcols + (j0 - wc.ci0);

        switch ((g.e[c].mth << 2) | g.e[c].mtw) {
            case (2 << 2) | 2: taps<2, 2>(rp0, wc.rcols, wh4, ww4, a0, a1, a2); break;
            case (3 << 2) | 2: taps<3, 2>(rp0, wc.rcols, wh4, ww4, a0, a1, a2); break;
            case (2 << 2) | 3: taps<2, 3>(rp0, wc.rcols, wh4, ww4, a0, a1, a2); break;
            case (3 << 2) | 3: taps<3, 3>(rp0, wc.rcols, wh4, ww4, a0, a1, a2); break;
            case (4 << 2) | 3: taps<4, 3>(rp0, wc.rcols, wh4, ww4, a0, a1, a2); break;
            case (3 << 2) | 4: taps<3, 4>(rp0, wc.rcols, wh4, ww4, a0, a1, a2); break;
            default:           taps<4, 4>(rp0, wc.rcols, wh4, ww4, a0, a1, a2); break;
        }
    }

    out[obase + 0] = a0;
    out[obase + 1] = a1;
    out[obase + 2] = a2;
}

// ---------------------------------------------------------------------------
// Host launch
// ---------------------------------------------------------------------------
extern "C" void kernel_launch(void* const* d_in, const int* in_sizes, int n_in,
                              void* d_out, int out_size, void* d_ws, size_t ws_size,
                              hipStream_t stream) {
    const float* x   = (const float*)d_in[0];
    const float* wp3 = (const float*)d_in[1];
    const float* wp4 = (const float*)d_in[2];
    const float* wp5 = (const float*)d_in[3];
    float* out = (float*)d_out;
    float4* wtbl = (float4*)d_ws;
    int*    itbl = (int*)((char*)d_ws + WTBL_BYTES);
    float4* wT   = (float4*)((char*)d_ws + WT_OFF_BYTES);
    uint2*  agg  = (uint2*)((char*)d_ws + AGG_OFF_BYTES);

    // Build the 21 configs exactly as the reference does (double precision).
    struct { int stride, size, nscale; double scales[3]; int gh; } layers[3] = {
        {32, 48, 2, {pow(2.0, 1.0 / 3.0), pow(2.0, 2.0 / 3.0), 0.0}, 14},
        {64, 96, 2, {pow(2.0, 1.0 / 3.0), pow(2.0, 2.0 / 3.0), 0.0}, 7},
        {128, 192, 3, {1.0, pow(2.0, 1.0 / 3.0), pow(2.0, 2.0 / 3.0)}, 4},
    };
    const double ars[3] = {0.667, 1.0, 1.5};

    struct HostCfg {
        int kh, kw, stride, p0, p1, gh, gw, layer, anchor, mth, mtw, wt_off;
        int qpr, blocks_per_img;
    } cfg[NCFG];
    TablesArgs ta;
    TrArgs tr;
    int nc = 0, wt_run = 0;
    for (int L = 0; L < 3; ++L) {
        int anchor = 0;
        for (int si = 0; si < layers[L].nscale; ++si) {
            for (int ai = 0; ai < 3; ++ai) {
                double ss = (double)layers[L].size * layers[L].scales[si];
                double sq = pow(ars[ai], 0.5);
                int kh = (int)(ss / sq);
                int kw = (int)(ss * sq);
                HostCfg& e = cfg[nc];
                e.kh = kh; e.kw = kw;
                e.stride = layers[L].stride;
                e.p0 = (int)ceil((double)(kh - layers[L].stride) / 2.0);
                e.p1 = (int)ceil((double)(kw - layers[L].stride) / 2.0);
                e.gh = layers[L].gh; e.gw = layers[L].gh;
                e.layer = L; e.anchor = anchor++;
                e.mth = (kh < OUT_HW) ? 2 : (int)((2.0 * kh) / OUT_HW) + 1;
                e.mtw = (kw < OUT_HW) ? 2 : (int)((2.0 * kw) / OUT_HW) + 1;
                if (e.mth > 4) e.mth = 4;
                if (e.mtw > 4) e.mtw = 4;
                e.qpr = (kw + 3) / 4;
                e.blocks_per_img = (kh * e.qpr + 255) / 256;
                e.wt_off = wt_run;
                int gsz = e.gh * e.gw;
                wt_run += BATCH * gsz;
                ta.kh[nc] = kh; ta.kw[nc] = kw;
                tr.layer[nc] = L; tr.anchor[nc] = e.anchor;
                tr.gsz[nc] = gsz; tr.wt_off[nc] = e.wt_off;
                ++nc;
            }
        }
    }

    init_tables<<<NCFG * 2, 256, 0, stream>>>(wtbl, itbl, ta);
    transpose_w<<<dim3(NCFG, BATCH), 256, 0, stream>>>(wp3, wp4, wp5, wT, tr);

    size_t cap_px = (ws_size - AGG_OFF_BYTES) / 8;
    dim3 rgrid(OUT_HW / 16, OUT_HW / 16, BATCH * KK);

    int i = 0;
    int first = 1;
    while (i < NCFG) {
        // build a group
        int gstart = i;
        size_t used = 0;
        while (i < NCFG) {
            size_t need = (size_t)cfg[i].kh * cfg[i].kw * (BATCH * KK);
            if (i > gstart && used + need > cap_px) break;
            used += need;
            ++i;
            if (used >= cap_px) break;
        }
        GroupArgs g; g.n = 0;
        AggArgs aa; aa.n = 0;
        int ablocks = 0;
        size_t off = 0;
        for (int c = gstart; c < i; ++c) {
            ACfg& lc = aa.e[aa.n++];
            lc.kh = cfg[c].kh; lc.kw = cfg[c].kw;
            lc.p0 = cfg[c].p0; lc.p1 = cfg[c].p1;
            lc.qpr = cfg[c].qpr;
            lc.layer = cfg[c].layer;
            lc.wt_off = cfg[c].wt_off;
            lc.ws_off = (int)off;
            lc.block_start = ablocks;
            lc.blocks_per_img = cfg[c].blocks_per_img;
            ablocks += cfg[c].blocks_per_img * BATCH;
            CfgEntry& re = g.e[g.n++];
            re.kh = cfg[c].kh; re.kw = cfg[c].kw;
            re.mth = cfg[c].mth; re.mtw = cfg[c].mtw;
            re.tbl = c; re.ws_off = (int)off;
            off += (size_t)cfg[c].kh * cfg[c].kw * (BATCH * KK);
        }
        agg_all<<<ablocks, 256, 0, stream>>>(x, wT, agg, aa);
        resize_kernel<<<rgrid, 256, 0, stream>>>(agg, wtbl, itbl, out, g, first ? 0 : 1);
        first = 0;
    }
    (void)in_sizes; (void)n_in; (void)out_size;
}

// Round 6
// 346.365 us; speedup vs baseline: 1.6855x; 1.6855x over previous
//
#include <hip/hip_runtime.h>
#include <math.h>

// ---------------------------------------------------------------------------
// AttentionNet weighted-anchor aggregator.
//   x:  (8, 448, 448, 3) f32
//   wp3:(8, 6, 4, 14, 14) f32   wp4:(8, 6, 4, 7, 7) f32   wp5:(8, 9, 4, 4, 4) f32
//   out:(32, 224, 224, 3) f32 = sum over 21 configs of
//        resize_bilinear( einsum('bkij,bihjwc->bkhwc', w, patches), 224,224 )
//
// Phase 0a: init_tables — normalized zero-padded 4-tap weights + i0.
// Phase 0b: transpose_w — weights to [cfg][b][grid][k0..k3] float4.
// Phase A : agg_all — ONE dispatch, runtime-uniform cfg params; weights in
//           LDS as float4 (1 broadcast ds_read_b128 per tap); 2 px/thread
//           (acc[2][4][3]=24 regs — occupancy-safe); per-thread valid i-range
//           precomputed; bf16x4 (8 B/px) out.
// Phase B : resize_kernel — pipelined cfg loop, region as uint2 bf16
//           (unchanged from round 5).
// ---------------------------------------------------------------------------

#define BATCH 8
#define KK 4
#define OUT_HW 224
#define IMG_HW 448
#define NCFG 21

#define WTBL_BYTES (NCFG * 2 * OUT_HW * 16)     // 150528
#define ITBL_BYTES (NCFG * 2 * OUT_HW * 4)      // 37632
#define WT_OFF_BYTES (WTBL_BYTES + ITBL_BYTES)  // 188160
#define WT_F4 12912                             // 8 * (6*196 + 6*49 + 9*16)
#define AGG_OFF_BYTES (WT_OFF_BYTES + WT_F4 * 16)  // 394752 (16B aligned)

#define REGION_PX 640                           // max window = 580 px

struct CfgEntry {          // resize view of a config
    int kh, kw;
    int mth, mtw;          // max tap count per dim (2..4)
    int tbl;               // global cfg index (table lookup)
    int ws_off;            // px (uint2) offset in agg region
};

struct GroupArgs {
    CfgEntry e[NCFG];
    int n;
};

struct ACfg {              // agg view of a config
    int kh, kw, p0, p1;
    int gh, gw, stride;
    int qpr;               // pairs (2px) per row = ceil(kw/2)
    int wt_off;            // float4 offset of transposed weights
    int ws_off;            // px offset in agg region
    int block_start;
    int blocks_per_img;    // ceil(kh*qpr/256)
};

struct AggArgs {
    ACfg e[NCFG];
    int n;
};

struct TablesArgs { int kh[NCFG]; int kw[NCFG]; };

struct TrArgs {
    int layer[NCFG];
    int anchor[NCFG];
    int gsz[NCFG];
    int wt_off[NCFG];
};

struct F3 { float a, b, c; };

__device__ inline unsigned int bf16_rne(float f) {
    unsigned int u = __float_as_uint(f);
    return (u + 0x7fffu + ((u >> 16) & 1u)) >> 16;
}

// ---------------------------------------------------------------------------
// Phase 0a: tap tables. jax.image.resize('bilinear', antialias=True):
//   inv=in/out; ks=max(inv,1); sf=(o+0.5)*inv-0.5; taps i in
//   [ceil(sf-ks), floor(sf+ks)] clamped, w=max(0,1-|i-sf|/ks) normalized.
// ---------------------------------------------------------------------------
__global__ __launch_bounds__(256) void init_tables(float4* __restrict__ wtbl,
                                                   int* __restrict__ itbl,
                                                   TablesArgs t) {
    int cfg = blockIdx.x >> 1;
    int dim = blockIdx.x & 1;
    int o = threadIdx.x;
    if (o >= OUT_HW) return;
    int n = dim ? t.kw[cfg] : t.kh[cfg];

    float inv = (float)(1.0 / ((double)OUT_HW / (double)n));
    float ks  = inv > 1.f ? inv : 1.f;
    float rks = 1.f / ks;
    float sf  = ((float)o + 0.5f) * inv - 0.5f;
    int i0 = (int)ceilf(sf - ks);  if (i0 < 0) i0 = 0;
    int i1 = (int)floorf(sf + ks); if (i1 > n - 1) i1 = n - 1;
    float sum = 0.f;
    for (int i = i0; i <= i1; ++i) {
        float v = 1.f - fabsf((float)i - sf) * rks;
        sum += (v > 0.f ? v : 0.f);
    }
    float rsum = 1.f / sum;
    float w[4];
#pragma unroll
    for (int d = 0; d < 4; ++d) {
        int i = i0 + d;
        float v = 0.f;
        if (i <= i1) {
            v = 1.f - fabsf((float)i - sf) * rks;
            v = (v > 0.f ? v : 0.f) * rsum;
        }
        w[d] = v;
    }
    int idx = cfg * (2 * OUT_HW) + dim * OUT_HW + o;
    wtbl[idx] = make_float4(w[0], w[1], w[2], w[3]);
    itbl[idx] = i0;
}

// ---------------------------------------------------------------------------
// Phase 0b: transpose weights (B,A,K,gh,gw) -> per cfg [b][g][k0..k3] float4.
// ---------------------------------------------------------------------------
__global__ __launch_bounds__(256) void transpose_w(
        const float* __restrict__ wp3, const float* __restrict__ wp4,
        const float* __restrict__ wp5, float4* __restrict__ wT, TrArgs t) {
    int cfg = blockIdx.x;
    int b = blockIdx.y;
    int gsz = t.gsz[cfg];
    const float* base;
    int A;
    if (t.layer[cfg] == 0)      { base = wp3; A = 6; }
    else if (t.layer[cfg] == 1) { base = wp4; A = 6; }
    else                        { base = wp5; A = 9; }
    const float* src = base + (size_t)(b * A + t.anchor[cfg]) * (KK * gsz);
    for (int g = threadIdx.x; g < gsz; g += 256) {
        wT[t.wt_off[cfg] + b * gsz + g] =
            make_float4(src[0 * gsz + g], src[1 * gsz + g],
                        src[2 * gsz + g], src[3 * gsz + g]);
    }
}

// ---------------------------------------------------------------------------
// Phase A: agg[bk, h, w] (bf16x4 in uint2) =
//   sum_{i,j} W[b,k,i,j] * X[b, i*s+h-p0, j*s+w-p1, :]
// One thread per (b, h, w-pair): 2 px, all 4 k, 3 c. Weights staged in LDS
// as float4 (one broadcast ds_read_b128 per tap). Valid i-range precomputed.
// ---------------------------------------------------------------------------
__global__ __launch_bounds__(256, 4) void agg_all(
        const float* __restrict__ x,
        const float4* __restrict__ wT,
        uint2* __restrict__ agg,
        AggArgs a) {
    int bid = blockIdx.x;
    int ci = 0;
    while (ci + 1 < a.n && bid >= a.e[ci + 1].block_start) ci++;
    const ACfg c = a.e[ci];
    int local = bid - c.block_start;
    int b     = local / c.blocks_per_img;
    int sblk  = local - b * c.blocks_per_img;

    const int gsz = c.gh * c.gw;
    __shared__ float4 wlds[196];
    for (int t = threadIdx.x; t < gsz; t += 256)
        wlds[t] = wT[c.wt_off + b * gsz + t];
    __syncthreads();

    int pidx = sblk * 256 + (int)threadIdx.x;
    if (pidx >= c.kh * c.qpr) return;
    int h  = pidx / c.qpr;
    int w0 = (pidx - h * c.qpr) * 2;

    const float* __restrict__ xb = x + (size_t)b * (IMG_HW * IMG_HW * 3);

    float acc[2][4][3] = {};

    const int s  = c.stride;
    const int rb = h - c.p0;
    // valid i range: 0 <= rb + i*s <= 447
    int ilo = rb >= 0 ? 0 : (-rb + s - 1) / s;
    int ihi = (IMG_HW - 1 - rb) / s;
    if (ihi > c.gh - 1) ihi = c.gh - 1;

    const int cb = w0 - c.p1;

    for (int i = ilo; i <= ihi; ++i) {
        const float* xr = xb + (size_t)(rb + i * s) * (IMG_HW * 3);
        const float4* wrow = wlds + i * c.gw;
        int col = cb;
        for (int j = 0; j < c.gw; ++j, col += s) {
            float4 wk = wrow[j];   // uniform address -> broadcast b128
#pragma unroll
            for (int t = 0; t < 2; ++t) {
                int ct = col + t;
                if ((unsigned)ct < (unsigned)IMG_HW) {
                    F3 v = *(const F3*)(xr + (size_t)ct * 3);
                    acc[t][0][0] = fmaf(wk.x, v.a, acc[t][0][0]);
                    acc[t][0][1] = fmaf(wk.x, v.b, acc[t][0][1]);
                    acc[t][0][2] = fmaf(wk.x, v.c, acc[t][0][2]);
                    acc[t][1][0] = fmaf(wk.y, v.a, acc[t][1][0]);
                    acc[t][1][1] = fmaf(wk.y, v.b, acc[t][1][1]);
                    acc[t][1][2] = fmaf(wk.y, v.c, acc[t][1][2]);
                    acc[t][2][0] = fmaf(wk.z, v.a, acc[t][2][0]);
                    acc[t][2][1] = fmaf(wk.z, v.b, acc[t][2][1]);
                    acc[t][2][2] = fmaf(wk.z, v.c, acc[t][2][2]);
                    acc[t][3][0] = fmaf(wk.w, v.a, acc[t][3][0]);
                    acc[t][3][1] = fmaf(wk.w, v.b, acc[t][3][1]);
                    acc[t][3][2] = fmaf(wk.w, v.c, acc[t][3][2]);
                }
            }
        }
    }

    const int npix = c.kh * c.kw;
    const bool two = (w0 + 1) < c.kw;
#pragma unroll
    for (int k = 0; k < 4; ++k) {
        size_t base = (size_t)c.ws_off + (size_t)(b * KK + k) * npix
                    + (size_t)h * c.kw + w0;
        uint2 o0;
        o0.x = bf16_rne(acc[0][k][0]) | (bf16_rne(acc[0][k][1]) << 16);
        o0.y = bf16_rne(acc[0][k][2]);
        agg[base] = o0;
        if (two) {
            uint2 o1;
            o1.x = bf16_rne(acc[1][k][0]) | (bf16_rne(acc[1][k][1]) << 16);
            o1.y = bf16_rne(acc[1][k][2]);
            agg[base + 1] = o1;
        }
    }
}

// ---------------------------------------------------------------------------
// Tap micro-kernel: TH x TW taps from the uint2 (bf16x3) LDS region.
// ---------------------------------------------------------------------------
template <int TH, int TW>
__device__ inline void taps(const uint2* __restrict__ rp0, int rcols,
                            float4 wh4, float4 ww4,
                            float& a0, float& a1, float& a2) {
    const float* wh = (const float*)&wh4;
    const float* ww = (const float*)&ww4;
#pragma unroll
    for (int d = 0; d < TH; ++d) {
        const uint2* rp = rp0 + d * rcols;
        float r0 = 0.f, r1 = 0.f, r2 = 0.f;
#pragma unroll
        for (int e = 0; e < TW; ++e) {
            uint2 v = rp[e];
            float c0 = __uint_as_float(v.x << 16);
            float c1 = __uint_as_float(v.x & 0xffff0000u);
            float c2 = __uint_as_float(v.y << 16);
            float w = ww[e];
            r0 = fmaf(w, c0, r0);
            r1 = fmaf(w, c1, r1);
            r2 = fmaf(w, c2, r2);
        }
        a0 = fmaf(wh[d], r0, a0);
        a1 = fmaf(wh[d], r1, a1);
        a2 = fmaf(wh[d], r2, a2);
    }
}

struct Win { int ri0, ci0, rrows, rcols; };

// ---------------------------------------------------------------------------
// Phase B: block = 16x16 output tile for one bk. Pipelined cfg loop:
//   round c: [barrier A] ds_write window c (from regs) [barrier B]
//            issue global loads for window c+1 -> regs; taps for cfg c.
// ---------------------------------------------------------------------------
__global__ __launch_bounds__(256) void resize_kernel(
        const uint2* __restrict__ agg,
        const float4* __restrict__ wtbl,
        const int* __restrict__ itbl,
        float* __restrict__ out,
        GroupArgs g, int accumulate) {
    const int tid = threadIdx.x;
    const int tx = tid & 15;
    const int ty = tid >> 4;
    const int xo = blockIdx.x * 16 + tx;
    const int yo = blockIdx.y * 16 + ty;
    const int bk = blockIdx.z;

    __shared__ float4 wlds[NCFG * 32];
    __shared__ int    ilds[NCFG * 32];
    __shared__ uint2  region[REGION_PX];

    const int nent = g.n * 32;
    for (int e = tid; e < nent; e += 256) {
        int ci  = e >> 5;
        int r   = e & 31;
        int isW = r >> 4;
        int idx = r & 15;
        int base_o = isW ? (blockIdx.x * 16) : (blockIdx.y * 16);
        int src = g.e[ci].tbl * (2 * OUT_HW) + isW * OUT_HW + base_o + idx;
        wlds[ci * 32 + r] = wtbl[src];
        ilds[ci * 32 + r] = itbl[src];
    }
    __syncthreads();

    const int scc = tid & 31;      // staging col lane
    const int srw = tid >> 5;      // staging row base (8 rows/step)

    uint2 sreg[4];
    Win wn, wc;

    // prologue: issue loads for cfg 0
    {
        const CfgEntry c0 = g.e[0];
        int ri0 = ilds[0 * 32 + 0];
        int ri1 = ilds[0 * 32 + 15] + c0.mth - 1;
        int ci0 = ilds[0 * 32 + 16];
        int ci1 = ilds[0 * 32 + 31] + c0.mtw - 1;
        wn.ri0 = ri0; wn.ci0 = ci0;
        wn.rrows = ri1 - ri0 + 1; wn.rcols = ci1 - ci0 + 1;
        const uint2* base = agg + (size_t)c0.ws_off + (size_t)bk * c0.kh * c0.kw;
        int gj = ci0 + scc; if (gj > c0.kw - 1) gj = c0.kw - 1;
        bool cok = scc < wn.rcols;
#pragma unroll
        for (int s = 0; s < 4; ++s) {
            int r = srw + s * 8;
            if (cok && r < wn.rrows) {
                int gi = ri0 + r; if (gi > c0.kh - 1) gi = c0.kh - 1;
                sreg[s] = base[(size_t)gi * c0.kw + gj];
            }
        }
    }

    size_t obase = (((size_t)bk * OUT_HW + yo) * OUT_HW + xo) * 3;
    float a0, a1, a2;
    if (accumulate) { a0 = out[obase]; a1 = out[obase + 1]; a2 = out[obase + 2]; }
    else            { a0 = 0.f; a1 = 0.f; a2 = 0.f; }

    for (int c = 0; c < g.n; ++c) {
        wc = wn;
        __syncthreads();   // A: taps c-1 done; sreg loads drained here
        {
            bool cok = scc < wc.rcols;
#pragma unroll
            for (int s = 0; s < 4; ++s) {
                int r = srw + s * 8;
                if (cok && r < wc.rrows)
                    region[r * wc.rcols + scc] = sreg[s];
            }
        }
        __syncthreads();   // B: region visible

        if (c + 1 < g.n) {
            const CfgEntry cn = g.e[c + 1];
            int ri0 = ilds[(c + 1) * 32 + 0];
            int ri1 = ilds[(c + 1) * 32 + 15] + cn.mth - 1;
            int ci0 = ilds[(c + 1) * 32 + 16];
            int ci1 = ilds[(c + 1) * 32 + 31] + cn.mtw - 1;
            wn.ri0 = ri0; wn.ci0 = ci0;
            wn.rrows = ri1 - ri0 + 1; wn.rcols = ci1 - ci0 + 1;
            const uint2* base = agg + (size_t)cn.ws_off + (size_t)bk * cn.kh * cn.kw;
            int gj = ci0 + scc; if (gj > cn.kw - 1) gj = cn.kw - 1;
            bool cok = scc < wn.rcols;
#pragma unroll
            for (int s = 0; s < 4; ++s) {
                int r = srw + s * 8;
                if (cok && r < wn.rrows) {
                    int gi = ri0 + r; if (gi > cn.kh - 1) gi = cn.kh - 1;
                    sreg[s] = base[(size_t)gi * cn.kw + gj];
                }
            }
        }

        // taps for cfg c
        float4 wh4 = wlds[c * 32 + ty];
        float4 ww4 = wlds[c * 32 + 16 + tx];
        int i0 = ilds[c * 32 + ty];
        int j0 = ilds[c * 32 + 16 + tx];
        const uint2* rp0 = region + (i0 - wc.ri0) * wc.rcols + (j0 - wc.ci0);

        switch ((g.e[c].mth << 2) | g.e[c].mtw) {
            case (2 << 2) | 2: taps<2, 2>(rp0, wc.rcols, wh4, ww4, a0, a1, a2); break;
            case (3 << 2) | 2: taps<3, 2>(rp0, wc.rcols, wh4, ww4, a0, a1, a2); break;
            case (2 << 2) | 3: taps<2, 3>(rp0, wc.rcols, wh4, ww4, a0, a1, a2); break;
            case (3 << 2) | 3: taps<3, 3>(rp0, wc.rcols, wh4, ww4, a0, a1, a2); break;
            case (4 << 2) | 3: taps<4, 3>(rp0, wc.rcols, wh4, ww4, a0, a1, a2); break;
            case (3 << 2) | 4: taps<3, 4>(rp0, wc.rcols, wh4, ww4, a0, a1, a2); break;
            default:           taps<4, 4>(rp0, wc.rcols, wh4, ww4, a0, a1, a2); break;
        }
    }

    out[obase + 0] = a0;
    out[obase + 1] = a1;
    out[obase + 2] = a2;
}

// ---------------------------------------------------------------------------
// Host launch
// ---------------------------------------------------------------------------
extern "C" void kernel_launch(void* const* d_in, const int* in_sizes, int n_in,
                              void* d_out, int out_size, void* d_ws, size_t ws_size,
                              hipStream_t stream) {
    const float* x   = (const float*)d_in[0];
    const float* wp3 = (const float*)d_in[1];
    const float* wp4 = (const float*)d_in[2];
    const float* wp5 = (const float*)d_in[3];
    float* out = (float*)d_out;
    float4* wtbl = (float4*)d_ws;
    int*    itbl = (int*)((char*)d_ws + WTBL_BYTES);
    float4* wT   = (float4*)((char*)d_ws + WT_OFF_BYTES);
    uint2*  agg  = (uint2*)((char*)d_ws + AGG_OFF_BYTES);

    // Build the 21 configs exactly as the reference does (double precision).
    struct { int stride, size, nscale; double scales[3]; int gh; } layers[3] = {
        {32, 48, 2, {pow(2.0, 1.0 / 3.0), pow(2.0, 2.0 / 3.0), 0.0}, 14},
        {64, 96, 2, {pow(2.0, 1.0 / 3.0), pow(2.0, 2.0 / 3.0), 0.0}, 7},
        {128, 192, 3, {1.0, pow(2.0, 1.0 / 3.0), pow(2.0, 2.0 / 3.0)}, 4},
    };
    const double ars[3] = {0.667, 1.0, 1.5};

    struct HostCfg {
        int kh, kw, stride, p0, p1, gh, gw, layer, anchor, mth, mtw, wt_off;
        int qpr, blocks_per_img;
    } cfg[NCFG];
    TablesArgs ta;
    TrArgs tr;
    int nc = 0, wt_run = 0;
    for (int L = 0; L < 3; ++L) {
        int anchor = 0;
        for (int si = 0; si < layers[L].nscale; ++si) {
            for (int ai = 0; ai < 3; ++ai) {
                double ss = (double)layers[L].size * layers[L].scales[si];
                double sq = pow(ars[ai], 0.5);
                int kh = (int)(ss / sq);
                int kw = (int)(ss * sq);
                HostCfg& e = cfg[nc];
                e.kh = kh; e.kw = kw;
                e.stride = layers[L].stride;
                e.p0 = (int)ceil((double)(kh - layers[L].stride) / 2.0);
                e.p1 = (int)ceil((double)(kw - layers[L].stride) / 2.0);
                e.gh = layers[L].gh; e.gw = layers[L].gh;
                e.layer = L; e.anchor = anchor++;
                e.mth = (kh < OUT_HW) ? 2 : (int)((2.0 * kh) / OUT_HW) + 1;
                e.mtw = (kw < OUT_HW) ? 2 : (int)((2.0 * kw) / OUT_HW) + 1;
                if (e.mth > 4) e.mth = 4;
                if (e.mtw > 4) e.mtw = 4;
                e.qpr = (kw + 1) / 2;
                e.blocks_per_img = (kh * e.qpr + 255) / 256;
                e.wt_off = wt_run;
                int gsz = e.gh * e.gw;
                wt_run += BATCH * gsz;
                ta.kh[nc] = kh; ta.kw[nc] = kw;
                tr.layer[nc] = L; tr.anchor[nc] = e.anchor;
                tr.gsz[nc] = gsz; tr.wt_off[nc] = e.wt_off;
                ++nc;
            }
        }
    }

    init_tables<<<NCFG * 2, 256, 0, stream>>>(wtbl, itbl, ta);
    transpose_w<<<dim3(NCFG, BATCH), 256, 0, stream>>>(wp3, wp4, wp5, wT, tr);

    size_t cap_px = (ws_size - AGG_OFF_BYTES) / 8;
    dim3 rgrid(OUT_HW / 16, OUT_HW / 16, BATCH * KK);

    int i = 0;
    int first = 1;
    while (i < NCFG) {
        // build a group
        int gstart = i;
        size_t used = 0;
        while (i < NCFG) {
            size_t need = (size_t)cfg[i].kh * cfg[i].kw * (BATCH * KK);
            if (i > gstart && used + need > cap_px) break;
            used += need;
            ++i;
            if (used >= cap_px) break;
        }
        GroupArgs g; g.n = 0;
        AggArgs aa; aa.n = 0;
        int ablocks = 0;
        size_t off = 0;
        for (int c = gstart; c < i; ++c) {
            ACfg& lc = aa.e[aa.n++];
            lc.kh = cfg[c].kh; lc.kw = cfg[c].kw;
            lc.p0 = cfg[c].p0; lc.p1 = cfg[c].p1;
            lc.gh = cfg[c].gh; lc.gw = cfg[c].gw;
            lc.stride = cfg[c].stride;
            lc.qpr = cfg[c].qpr;
            lc.wt_off = cfg[c].wt_off;
            lc.ws_off = (int)off;
            lc.block_start = ablocks;
            lc.blocks_per_img = cfg[c].blocks_per_img;
            ablocks += cfg[c].blocks_per_img * BATCH;
            CfgEntry& re = g.e[g.n++];
            re.kh = cfg[c].kh; re.kw = cfg[c].kw;
            re.mth = cfg[c].mth; re.mtw = cfg[c].mtw;
            re.tbl = c; re.ws_off = (int)off;
            off += (size_t)cfg[c].kh * cfg[c].kw * (BATCH * KK);
        }
        agg_all<<<ablocks, 256, 0, stream>>>(x, wT, agg, aa);
        resize_kernel<<<rgrid, 256, 0, stream>>>(agg, wtbl, itbl, out, g, first ? 0 : 1);
        first = 0;
    }
    (void)in_sizes; (void)n_in; (void)out_size;
}

// Round 7
// 330.584 us; speedup vs baseline: 1.7659x; 1.0477x over previous
//
#include <hip/hip_runtime.h>
#include <math.h>

// ---------------------------------------------------------------------------
// AttentionNet weighted-anchor aggregator.
//   x:  (8, 448, 448, 3) f32
//   wp3:(8, 6, 4, 14, 14) f32   wp4:(8, 6, 4, 7, 7) f32   wp5:(8, 9, 4, 4, 4) f32
//   out:(32, 224, 224, 3) f32 = sum over 21 configs of
//        resize_bilinear( einsum('bkij,bihjwc->bkhwc', w, patches), 224,224 )
//
// Phase 0a: init_tables — normalized zero-padded 4-tap weights + i0.
// Phase 0b: transpose_w — weights to [cfg][b][grid][k0..k3] float4.
// Phase A : agg_all — ONE dispatch, block-uniform layer switch into templated
//           <GH,GW,STRIDE> bodies (full j-unroll => batched loads); 2px/thread
//           fetched as one 24B F6 load; weights via broadcast ds_read_b128;
//           bf16x4 (8 B/px) out.
// Phase B : resize_kernel — pipelined cfg loop, 2 bk per block (window coords
//           shared, data double-buffered) to amortize barrier-stall rounds.
// ---------------------------------------------------------------------------

#define BATCH 8
#define KK 4
#define OUT_HW 224
#define IMG_HW 448
#define NCFG 21

#define WTBL_BYTES (NCFG * 2 * OUT_HW * 16)     // 150528
#define ITBL_BYTES (NCFG * 2 * OUT_HW * 4)      // 37632
#define WT_OFF_BYTES (WTBL_BYTES + ITBL_BYTES)  // 188160
#define WT_F4 12912                             // 8 * (6*196 + 6*49 + 9*16)
#define AGG_OFF_BYTES (WT_OFF_BYTES + WT_F4 * 16)  // 394752 (16B aligned)

#define REGION_PX 640                           // max window = ~625 px

struct CfgEntry {          // resize view of a config
    int kh, kw;
    int mth, mtw;          // max tap count per dim (2..4)
    int tbl;               // global cfg index (table lookup)
    int ws_off;            // px (uint2) offset in agg region
};

struct GroupArgs {
    CfgEntry e[NCFG];
    int n;
};

struct ACfg {              // agg view of a config
    int kh, kw, p0, p1;
    int layer;             // 0=p3, 1=p4, 2=p5
    int qpr;               // pairs (2px) per row = ceil(kw/2)
    int wt_off;            // float4 offset of transposed weights
    int ws_off;            // px offset in agg region
    int block_start;
    int blocks_per_img;    // ceil(kh*qpr/256)
};

struct AggArgs {
    ACfg e[NCFG];
    int n;
};

struct TablesArgs { int kh[NCFG]; int kw[NCFG]; };

struct TrArgs {
    int layer[NCFG];
    int anchor[NCFG];
    int gsz[NCFG];
    int wt_off[NCFG];
};

struct F3 { float a, b, c; };
struct F6 { float f[6]; };

__device__ inline unsigned int bf16_rne(float f) {
    unsigned int u = __float_as_uint(f);
    return (u + 0x7fffu + ((u >> 16) & 1u)) >> 16;
}

// ---------------------------------------------------------------------------
// Phase 0a: tap tables. jax.image.resize('bilinear', antialias=True):
//   inv=in/out; ks=max(inv,1); sf=(o+0.5)*inv-0.5; taps i in
//   [ceil(sf-ks), floor(sf+ks)] clamped, w=max(0,1-|i-sf|/ks) normalized.
// ---------------------------------------------------------------------------
__global__ __launch_bounds__(256) void init_tables(float4* __restrict__ wtbl,
                                                   int* __restrict__ itbl,
                                                   TablesArgs t) {
    int cfg = blockIdx.x >> 1;
    int dim = blockIdx.x & 1;
    int o = threadIdx.x;
    if (o >= OUT_HW) return;
    int n = dim ? t.kw[cfg] : t.kh[cfg];

    float inv = (float)(1.0 / ((double)OUT_HW / (double)n));
    float ks  = inv > 1.f ? inv : 1.f;
    float rks = 1.f / ks;
    float sf  = ((float)o + 0.5f) * inv - 0.5f;
    int i0 = (int)ceilf(sf - ks);  if (i0 < 0) i0 = 0;
    int i1 = (int)floorf(sf + ks); if (i1 > n - 1) i1 = n - 1;
    float sum = 0.f;
    for (int i = i0; i <= i1; ++i) {
        float v = 1.f - fabsf((float)i - sf) * rks;
        sum += (v > 0.f ? v : 0.f);
    }
    float rsum = 1.f / sum;
    float w[4];
#pragma unroll
    for (int d = 0; d < 4; ++d) {
        int i = i0 + d;
        float v = 0.f;
        if (i <= i1) {
            v = 1.f - fabsf((float)i - sf) * rks;
            v = (v > 0.f ? v : 0.f) * rsum;
        }
        w[d] = v;
    }
    int idx = cfg * (2 * OUT_HW) + dim * OUT_HW + o;
    wtbl[idx] = make_float4(w[0], w[1], w[2], w[3]);
    itbl[idx] = i0;
}

// ---------------------------------------------------------------------------
// Phase 0b: transpose weights (B,A,K,gh,gw) -> per cfg [b][g][k0..k3] float4.
// ---------------------------------------------------------------------------
__global__ __launch_bounds__(256) void transpose_w(
        const float* __restrict__ wp3, const float* __restrict__ wp4,
        const float* __restrict__ wp5, float4* __restrict__ wT, TrArgs t) {
    int cfg = blockIdx.x;
    int b = blockIdx.y;
    int gsz = t.gsz[cfg];
    const float* base;
    int A;
    if (t.layer[cfg] == 0)      { base = wp3; A = 6; }
    else if (t.layer[cfg] == 1) { base = wp4; A = 6; }
    else                        { base = wp5; A = 9; }
    const float* src = base + (size_t)(b * A + t.anchor[cfg]) * (KK * gsz);
    for (int g = threadIdx.x; g < gsz; g += 256) {
        wT[t.wt_off[cfg] + b * gsz + g] =
            make_float4(src[0 * gsz + g], src[1 * gsz + g],
                        src[2 * gsz + g], src[3 * gsz + g]);
    }
}

// ---------------------------------------------------------------------------
// Agg body (templated): 2 consecutive px per thread, acc[2][4][3].
// Interior pair fetched as one 24B F6 load (dwordx4 + dwordx2).
// ---------------------------------------------------------------------------
template <int GH, int GW, int STRIDE>
__device__ inline void agg_body(const ACfg& c, int b, int h, int w0,
                                const float* __restrict__ xb,
                                const float4* __restrict__ wlds,
                                uint2* __restrict__ agg) {
    float acc[2][4][3] = {};

    const int rb = h - c.p0;
    // valid i range: 0 <= rb + i*STRIDE <= IMG_HW-1
    int ilo = rb >= 0 ? 0 : (-rb + STRIDE - 1) / STRIDE;
    int ihi = (IMG_HW - 1 - rb) / STRIDE;
    if (ihi > GH - 1) ihi = GH - 1;

    const int cb = w0 - c.p1;

#pragma unroll 1
    for (int i = ilo; i <= ihi; ++i) {
        const float* xr = xb + (size_t)(rb + i * STRIDE) * (IMG_HW * 3);
        const float4* wrow = wlds + i * GW;
#pragma unroll
        for (int j = 0; j < GW; ++j) {
            int col = cb + j * STRIDE;
            float xv[6];
            bool any;
            if ((unsigned)col <= (unsigned)(IMG_HW - 2)) {
                F6 v = *(const F6*)(xr + (size_t)col * 3);
#pragma unroll
                for (int q = 0; q < 6; ++q) xv[q] = v.f[q];
                any = true;
            } else {
                bool ok0 = (unsigned)col < (unsigned)IMG_HW;        // col==447 or neg
                bool ok1 = (unsigned)(col + 1) < (unsigned)IMG_HW;  // col==-1
                any = ok0 || ok1;
#pragma unroll
                for (int q = 0; q < 6; ++q) xv[q] = 0.f;
                if (ok0) {
                    F3 v = *(const F3*)(xr + (size_t)col * 3);
                    xv[0] = v.a; xv[1] = v.b; xv[2] = v.c;
                }
                if (ok1) {
                    F3 v = *(const F3*)(xr + (size_t)(col + 1) * 3);
                    xv[3] = v.a; xv[4] = v.b; xv[5] = v.c;
                }
            }
            if (any) {
                float4 wk = wrow[j];   // uniform address -> broadcast b128
#pragma unroll
                for (int t = 0; t < 2; ++t) {
                    float x0 = xv[t * 3 + 0], x1 = xv[t * 3 + 1], x2 = xv[t * 3 + 2];
                    acc[t][0][0] = fmaf(wk.x, x0, acc[t][0][0]);
                    acc[t][0][1] = fmaf(wk.x, x1, acc[t][0][1]);
                    acc[t][0][2] = fmaf(wk.x, x2, acc[t][0][2]);
                    acc[t][1][0] = fmaf(wk.y, x0, acc[t][1][0]);
                    acc[t][1][1] = fmaf(wk.y, x1, acc[t][1][1]);
                    acc[t][1][2] = fmaf(wk.y, x2, acc[t][1][2]);
                    acc[t][2][0] = fmaf(wk.z, x0, acc[t][2][0]);
                    acc[t][2][1] = fmaf(wk.z, x1, acc[t][2][1]);
                    acc[t][2][2] = fmaf(wk.z, x2, acc[t][2][2]);
                    acc[t][3][0] = fmaf(wk.w, x0, acc[t][3][0]);
                    acc[t][3][1] = fmaf(wk.w, x1, acc[t][3][1]);
                    acc[t][3][2] = fmaf(wk.w, x2, acc[t][3][2]);
                }
            }
        }
    }

    const int npix = c.kh * c.kw;
    const bool two = (w0 + 1) < c.kw;
#pragma unroll
    for (int k = 0; k < 4; ++k) {
        size_t base = (size_t)c.ws_off + (size_t)(b * KK + k) * npix
                    + (size_t)h * c.kw + w0;
        uint2 o0;
        o0.x = bf16_rne(acc[0][k][0]) | (bf16_rne(acc[0][k][1]) << 16);
        o0.y = bf16_rne(acc[0][k][2]);
        agg[base] = o0;
        if (two) {
            uint2 o1;
            o1.x = bf16_rne(acc[1][k][0]) | (bf16_rne(acc[1][k][1]) << 16);
            o1.y = bf16_rne(acc[1][k][2]);
            agg[base + 1] = o1;
        }
    }
}

// ---------------------------------------------------------------------------
// Phase A: one dispatch for all configs; block-uniform layer switch.
// ---------------------------------------------------------------------------
__global__ __launch_bounds__(256, 4) void agg_all(
        const float* __restrict__ x,
        const float4* __restrict__ wT,
        uint2* __restrict__ agg,
        AggArgs a) {
    int bid = blockIdx.x;
    int ci = 0;
    while (ci + 1 < a.n && bid >= a.e[ci + 1].block_start) ci++;
    const ACfg c = a.e[ci];
    int local = bid - c.block_start;
    int b     = local / c.blocks_per_img;
    int sblk  = local - b * c.blocks_per_img;

    const int gsz = (c.layer == 0) ? 196 : (c.layer == 1) ? 49 : 16;
    __shared__ float4 wlds[196];
    for (int t = threadIdx.x; t < gsz; t += 256)
        wlds[t] = wT[c.wt_off + b * gsz + t];
    __syncthreads();

    int pidx = sblk * 256 + (int)threadIdx.x;
    if (pidx >= c.kh * c.qpr) return;
    int h  = pidx / c.qpr;
    int w0 = (pidx - h * c.qpr) * 2;

    const float* __restrict__ xb = x + (size_t)b * (IMG_HW * IMG_HW * 3);
    if (c.layer == 0)      agg_body<14, 14, 32>(c, b, h, w0, xb, wlds, agg);
    else if (c.layer == 1) agg_body<7, 7, 64>(c, b, h, w0, xb, wlds, agg);
    else                   agg_body<4, 4, 128>(c, b, h, w0, xb, wlds, agg);
}

// ---------------------------------------------------------------------------
// Tap micro-kernel: TH x TW taps from the uint2 (bf16x3) LDS region.
// ---------------------------------------------------------------------------
template <int TH, int TW>
__device__ inline void taps(const uint2* __restrict__ rp0, int rcols,
                            float4 wh4, float4 ww4,
                            float& a0, float& a1, float& a2) {
    const float* wh = (const float*)&wh4;
    const float* ww = (const float*)&ww4;
#pragma unroll
    for (int d = 0; d < TH; ++d) {
        const uint2* rp = rp0 + d * rcols;
        float r0 = 0.f, r1 = 0.f, r2 = 0.f;
#pragma unroll
        for (int e = 0; e < TW; ++e) {
            uint2 v = rp[e];
            float c0 = __uint_as_float(v.x << 16);
            float c1 = __uint_as_float(v.x & 0xffff0000u);
            float c2 = __uint_as_float(v.y << 16);
            float w = ww[e];
            r0 = fmaf(w, c0, r0);
            r1 = fmaf(w, c1, r1);
            r2 = fmaf(w, c2, r2);
        }
        a0 = fmaf(wh[d], r0, a0);
        a1 = fmaf(wh[d], r1, a1);
        a2 = fmaf(wh[d], r2, a2);
    }
}

struct Win { int ri0, ci0, rrows, rcols; };

// ---------------------------------------------------------------------------
// Phase B: block = 16x16 output tile for TWO bk (window coords shared, data
// double-buffered). Pipelined cfg loop:
//   round c: [barrier A] ds_write windows c (from regs) [barrier B]
//            issue global loads for windows c+1 -> regs; taps for cfg c (x2).
// ---------------------------------------------------------------------------
__global__ __launch_bounds__(256) void resize_kernel(
        const uint2* __restrict__ agg,
        const float4* __restrict__ wtbl,
        const int* __restrict__ itbl,
        float* __restrict__ out,
        GroupArgs g, int accumulate) {
    const int tid = threadIdx.x;
    const int tx = tid & 15;
    const int ty = tid >> 4;
    const int xo = blockIdx.x * 16 + tx;
    const int yo = blockIdx.y * 16 + ty;
    const int bk0 = blockIdx.z * 2;

    __shared__ float4 wlds[NCFG * 32];
    __shared__ int    ilds[NCFG * 32];
    __shared__ uint2  region[2 * REGION_PX];

    const int nent = g.n * 32;
    for (int e = tid; e < nent; e += 256) {
        int ci  = e >> 5;
        int r   = e & 31;
        int isW = r >> 4;
        int idx = r & 15;
        int base_o = isW ? (blockIdx.x * 16) : (blockIdx.y * 16);
        int src = g.e[ci].tbl * (2 * OUT_HW) + isW * OUT_HW + base_o + idx;
        wlds[ci * 32 + r] = wtbl[src];
        ilds[ci * 32 + r] = itbl[src];
    }
    __syncthreads();

    const int scc = tid & 31;      // staging col lane
    const int srw = tid >> 5;      // staging row base (8 rows/step)

    uint2 sreg[2][4];
    Win wn, wc;

    // prologue: issue loads for cfg 0 (both bk)
    {
        const CfgEntry c0 = g.e[0];
        int ri0 = ilds[0 * 32 + 0];
        int ri1 = ilds[0 * 32 + 15] + c0.mth - 1;
        int ci0 = ilds[0 * 32 + 16];
        int ci1 = ilds[0 * 32 + 31] + c0.mtw - 1;
        wn.ri0 = ri0; wn.ci0 = ci0;
        wn.rrows = ri1 - ri0 + 1; wn.rcols = ci1 - ci0 + 1;
        const int npx = c0.kh * c0.kw;
        const uint2* base = agg + (size_t)c0.ws_off + (size_t)bk0 * npx;
        int gj = ci0 + scc; if (gj > c0.kw - 1) gj = c0.kw - 1;
        bool cok = scc < wn.rcols;
#pragma unroll
        for (int s = 0; s < 4; ++s) {
            int r = srw + s * 8;
            if (cok && r < wn.rrows) {
                int gi = ri0 + r; if (gi > c0.kh - 1) gi = c0.kh - 1;
                size_t o = (size_t)gi * c0.kw + gj;
                sreg[0][s] = base[o];
                sreg[1][s] = base[o + npx];
            }
        }
    }

    size_t ob0 = (((size_t)bk0 * OUT_HW + yo) * OUT_HW + xo) * 3;
    size_t ob1 = ob0 + (size_t)OUT_HW * OUT_HW * 3;
    float a0, a1, a2, b0, b1, b2;
    if (accumulate) {
        a0 = out[ob0]; a1 = out[ob0 + 1]; a2 = out[ob0 + 2];
        b0 = out[ob1]; b1 = out[ob1 + 1]; b2 = out[ob1 + 2];
    } else {
        a0 = a1 = a2 = b0 = b1 = b2 = 0.f;
    }

    for (int c = 0; c < g.n; ++c) {
        wc = wn;
        __syncthreads();   // A: taps c-1 done; sreg loads drained here
        {
            bool cok = scc < wc.rcols;
#pragma unroll
            for (int s = 0; s < 4; ++s) {
                int r = srw + s * 8;
                if (cok && r < wc.rrows) {
                    int o = r * wc.rcols + scc;
                    region[o] = sreg[0][s];
                    region[REGION_PX + o] = sreg[1][s];
                }
            }
        }
        __syncthreads();   // B: region visible

        if (c + 1 < g.n) {
            const CfgEntry cn = g.e[c + 1];
            int ri0 = ilds[(c + 1) * 32 + 0];
            int ri1 = ilds[(c + 1) * 32 + 15] + cn.mth - 1;
            int ci0 = ilds[(c + 1) * 32 + 16];
            int ci1 = ilds[(c + 1) * 32 + 31] + cn.mtw - 1;
            wn.ri0 = ri0; wn.ci0 = ci0;
            wn.rrows = ri1 - ri0 + 1; wn.rcols = ci1 - ci0 + 1;
            const int npx = cn.kh * cn.kw;
            const uint2* base = agg + (size_t)cn.ws_off + (size_t)bk0 * npx;
            int gj = ci0 + scc; if (gj > cn.kw - 1) gj = cn.kw - 1;
            bool cok = scc < wn.rcols;
#pragma unroll
            for (int s = 0; s < 4; ++s) {
                int r = srw + s * 8;
                if (cok && r < wn.rrows) {
                    int gi = ri0 + r; if (gi > cn.kh - 1) gi = cn.kh - 1;
                    size_t o = (size_t)gi * cn.kw + gj;
                    sreg[0][s] = base[o];
                    sreg[1][s] = base[o + npx];
                }
            }
        }

        // taps for cfg c, both bk
        float4 wh4 = wlds[c * 32 + ty];
        float4 ww4 = wlds[c * 32 + 16 + tx];
        int i0 = ilds[c * 32 + ty];
        int j0 = ilds[c * 32 + 16 + tx];
        int roff = (i0 - wc.ri0) * wc.rcols + (j0 - wc.ci0);
        const uint2* rp0 = region + roff;
        const uint2* rp1 = region + REGION_PX + roff;

        switch ((g.e[c].mth << 2) | g.e[c].mtw) {
            case (2 << 2) | 2:
                taps<2, 2>(rp0, wc.rcols, wh4, ww4, a0, a1, a2);
                taps<2, 2>(rp1, wc.rcols, wh4, ww4, b0, b1, b2); break;
            case (3 << 2) | 2:
                taps<3, 2>(rp0, wc.rcols, wh4, ww4, a0, a1, a2);
                taps<3, 2>(rp1, wc.rcols, wh4, ww4, b0, b1, b2); break;
            case (2 << 2) | 3:
                taps<2, 3>(rp0, wc.rcols, wh4, ww4, a0, a1, a2);
                taps<2, 3>(rp1, wc.rcols, wh4, ww4, b0, b1, b2); break;
            case (3 << 2) | 3:
                taps<3, 3>(rp0, wc.rcols, wh4, ww4, a0, a1, a2);
                taps<3, 3>(rp1, wc.rcols, wh4, ww4, b0, b1, b2); break;
            case (4 << 2) | 3:
                taps<4, 3>(rp0, wc.rcols, wh4, ww4, a0, a1, a2);
                taps<4, 3>(rp1, wc.rcols, wh4, ww4, b0, b1, b2); break;
            case (3 << 2) | 4:
                taps<3, 4>(rp0, wc.rcols, wh4, ww4, a0, a1, a2);
                taps<3, 4>(rp1, wc.rcols, wh4, ww4, b0, b1, b2); break;
            default:
                taps<4, 4>(rp0, wc.rcols, wh4, ww4, a0, a1, a2);
                taps<4, 4>(rp1, wc.rcols, wh4, ww4, b0, b1, b2); break;
        }
    }

    out[ob0 + 0] = a0; out[ob0 + 1] = a1; out[ob0 + 2] = a2;
    out[ob1 + 0] = b0; out[ob1 + 1] = b1; out[ob1 + 2] = b2;
}

// ---------------------------------------------------------------------------
// Host launch
// ---------------------------------------------------------------------------
extern "C" void kernel_launch(void* const* d_in, const int* in_sizes, int n_in,
                              void* d_out, int out_size, void* d_ws, size_t ws_size,
                              hipStream_t stream) {
    const float* x   = (const float*)d_in[0];
    const float* wp3 = (const float*)d_in[1];
    const float* wp4 = (const float*)d_in[2];
    const float* wp5 = (const float*)d_in[3];
    float* out = (float*)d_out;
    float4* wtbl = (float4*)d_ws;
    int*    itbl = (int*)((char*)d_ws + WTBL_BYTES);
    float4* wT   = (float4*)((char*)d_ws + WT_OFF_BYTES);
    uint2*  agg  = (uint2*)((char*)d_ws + AGG_OFF_BYTES);

    // Build the 21 configs exactly as the reference does (double precision).
    struct { int stride, size, nscale; double scales[3]; int gh; } layers[3] = {
        {32, 48, 2, {pow(2.0, 1.0 / 3.0), pow(2.0, 2.0 / 3.0), 0.0}, 14},
        {64, 96, 2, {pow(2.0, 1.0 / 3.0), pow(2.0, 2.0 / 3.0), 0.0}, 7},
        {128, 192, 3, {1.0, pow(2.0, 1.0 / 3.0), pow(2.0, 2.0 / 3.0)}, 4},
    };
    const double ars[3] = {0.667, 1.0, 1.5};

    struct HostCfg {
        int kh, kw, stride, p0, p1, gh, gw, layer, anchor, mth, mtw, wt_off;
        int qpr, blocks_per_img;
    } cfg[NCFG];
    TablesArgs ta;
    TrArgs tr;
    int nc = 0, wt_run = 0;
    for (int L = 0; L < 3; ++L) {
        int anchor = 0;
        for (int si = 0; si < layers[L].nscale; ++si) {
            for (int ai = 0; ai < 3; ++ai) {
                double ss = (double)layers[L].size * layers[L].scales[si];
                double sq = pow(ars[ai], 0.5);
                int kh = (int)(ss / sq);
                int kw = (int)(ss * sq);
                HostCfg& e = cfg[nc];
                e.kh = kh; e.kw = kw;
                e.stride = layers[L].stride;
                e.p0 = (int)ceil((double)(kh - layers[L].stride) / 2.0);
                e.p1 = (int)ceil((double)(kw - layers[L].stride) / 2.0);
                e.gh = layers[L].gh; e.gw = layers[L].gh;
                e.layer = L; e.anchor = anchor++;
                e.mth = (kh < OUT_HW) ? 2 : (int)((2.0 * kh) / OUT_HW) + 1;
                e.mtw = (kw < OUT_HW) ? 2 : (int)((2.0 * kw) / OUT_HW) + 1;
                if (e.mth > 4) e.mth = 4;
                if (e.mtw > 4) e.mtw = 4;
                e.qpr = (kw + 1) / 2;
                e.blocks_per_img = (kh * e.qpr + 255) / 256;
                e.wt_off = wt_run;
                int gsz = e.gh * e.gw;
                wt_run += BATCH * gsz;
                ta.kh[nc] = kh; ta.kw[nc] = kw;
                tr.layer[nc] = L; tr.anchor[nc] = e.anchor;
                tr.gsz[nc] = gsz; tr.wt_off[nc] = e.wt_off;
                ++nc;
            }
        }
    }

    init_tables<<<NCFG * 2, 256, 0, stream>>>(wtbl, itbl, ta);
    transpose_w<<<dim3(NCFG, BATCH), 256, 0, stream>>>(wp3, wp4, wp5, wT, tr);

    size_t cap_px = (ws_size - AGG_OFF_BYTES) / 8;
    dim3 rgrid(OUT_HW / 16, OUT_HW / 16, BATCH * KK / 2);

    int i = 0;
    int first = 1;
    while (i < NCFG) {
        // build a group
        int gstart = i;
        size_t used = 0;
        while (i < NCFG) {
            size_t need = (size_t)cfg[i].kh * cfg[i].kw * (BATCH * KK);
            if (i > gstart && used + need > cap_px) break;
            used += need;
            ++i;
            if (used >= cap_px) break;
        }
        GroupArgs g; g.n = 0;
        AggArgs aa; aa.n = 0;
        int ablocks = 0;
        size_t off = 0;
        for (int c = gstart; c < i; ++c) {
            ACfg& lc = aa.e[aa.n++];
            lc.kh = cfg[c].kh; lc.kw = cfg[c].kw;
            lc.p0 = cfg[c].p0; lc.p1 = cfg[c].p1;
            lc.layer = cfg[c].layer;
            lc.qpr = cfg[c].qpr;
            lc.wt_off = cfg[c].wt_off;
            lc.ws_off = (int)off;
            lc.block_start = ablocks;
            lc.blocks_per_img = cfg[c].blocks_per_img;
            ablocks += cfg[c].blocks_per_img * BATCH;
            CfgEntry& re = g.e[g.n++];
            re.kh = cfg[c].kh; re.kw = cfg[c].kw;
            re.mth = cfg[c].mth; re.mtw = cfg[c].mtw;
            re.tbl = c; re.ws_off = (int)off;
            off += (size_t)cfg[c].kh * cfg[c].kw * (BATCH * KK);
        }
        agg_all<<<ablocks, 256, 0, stream>>>(x, wT, agg, aa);
        resize_kernel<<<rgrid, 256, 0, stream>>>(agg, wtbl, itbl, out, g, first ? 0 : 1);
        first = 0;
    }
    (void)in_sizes; (void)n_in; (void)out_size;
}